// Round 3
// baseline (444.512 us; speedup 1.0000x reference)
//
#include <hip/hip_runtime.h>
#include <math.h>

#define D        2048
#define E        64
#define NROWS    16384      // B*S = 4*4096
#define BK       64         // k-tile
#define KITERS   (D / BK)   // 32
#define XSTRIDE  68         // floats; 272 B row stride, 16B-aligned (b128 ok)

// ---------------- K1: logits = (x * factor) @ W^T + 0.1*noise ----------------
// 256 blocks x 512 threads (8 waves). lane = row (64 rows/block), wave w owns
// experts [8w, 8w+8). W operands are wave-uniform -> scalar s_load pipe (no
// LDS, no VALU). x staged global->LDS async (width=4, one instr per row),
// double-buffered; compute reads ONE ds_read_b128 per 4k per lane.
// Accumulation is strictly k-ascending fmac per output -> logits bit-identical
// to the round-2 passing kernel (no top-k tie re-rolls).
__global__ __launch_bounds__(512)
void gemm_kernel(const float* __restrict__ x,
                 const float* __restrict__ W,
                 const float* __restrict__ scond,
                 const float* __restrict__ noise,
                 const int* __restrict__ sidx,
                 float* __restrict__ logits_out)
{
    __shared__ float xs[2][64 * XSTRIDE];   // 2 x 17408 B

    const int tid  = threadIdx.x;
    const int lane = tid & 63;
    const int wv   = tid >> 6;              // 0..7
    const int rowBase = blockIdx.x * 64;

    // wave-uniform expert base, forced into an SGPR so W loads scalarize
    const int e0 = __builtin_amdgcn_readfirstlane(wv << 3);

    const float factor = 1.0f + 0.1f * scond[sidx[0]];

    float acc[8];
#pragma unroll
    for (int j = 0; j < 8; ++j) acc[j] = 0.f;

    // ---- stage tile 0 into buf 0: one global_load_lds per row (wave-uniform
    // LDS base + lane*4; source = 256 B contiguous row chunk) ----
#pragma unroll
    for (int rr = 0; rr < 8; ++rr) {
        const int r = (wv << 3) + rr;
        const float* src = x + (size_t)(rowBase + r) * D + lane;
        __builtin_amdgcn_global_load_lds(
            (const __attribute__((address_space(1))) void*)src,
            (__attribute__((address_space(3))) void*)&xs[0][r * XSTRIDE],
            4, 0, 0);
    }
    __syncthreads();   // compiler inserts vmcnt(0) drain before barrier

    for (int t = 0; t < KITERS; ++t) {
        const int cur = t & 1;

        // async-stage tile t+1 into the other buffer
        if (t + 1 < KITERS) {
            const int nxt = cur ^ 1;
            const int kOff = (t + 1) * BK;
#pragma unroll
            for (int rr = 0; rr < 8; ++rr) {
                const int r = (wv << 3) + rr;
                const float* src = x + (size_t)(rowBase + r) * D + kOff + lane;
                __builtin_amdgcn_global_load_lds(
                    (const __attribute__((address_space(1))) void*)src,
                    (__attribute__((address_space(3))) void*)&xs[nxt][r * XSTRIDE],
                    4, 0, 0);
            }
        }

        // compute tile t: per kg: 1 ds_read_b128 (x) + 8 scalar float4 (W)
        // + 4 v_mul + 32 v_fmac
        const float4* xrow = (const float4*)&xs[cur][lane * XSTRIDE];
        const float*  wbaseT = W + (size_t)e0 * D + t * BK;
#pragma unroll
        for (int kg = 0; kg < 16; ++kg) {
            float4 xv = xrow[kg];
            xv.x *= factor; xv.y *= factor; xv.z *= factor; xv.w *= factor;
            const float* wb = wbaseT + (kg << 2);
#pragma unroll
            for (int j = 0; j < 8; ++j) {
                const float4 wq = *(const float4*)(wb + (size_t)j * D);
                acc[j] += xv.x * wq.x;
                acc[j] += xv.y * wq.y;
                acc[j] += xv.z * wq.z;
                acc[j] += xv.w * wq.w;
            }
        }
        __syncthreads();
    }

    // epilogue: logits = acc + 0.1*noise
    const int gRow = rowBase + lane;
    const float4 n0 = *(const float4*)(noise + (size_t)gRow * E + e0);
    const float4 n1 = *(const float4*)(noise + (size_t)gRow * E + e0 + 4);
    float4 o0, o1;
    o0.x = acc[0] + 0.1f * n0.x;
    o0.y = acc[1] + 0.1f * n0.y;
    o0.z = acc[2] + 0.1f * n0.z;
    o0.w = acc[3] + 0.1f * n0.w;
    o1.x = acc[4] + 0.1f * n1.x;
    o1.y = acc[5] + 0.1f * n1.y;
    o1.z = acc[6] + 0.1f * n1.z;
    o1.w = acc[7] + 0.1f * n1.w;
    *(float4*)(logits_out + (size_t)gRow * E + e0)     = o0;
    *(float4*)(logits_out + (size_t)gRow * E + e0 + 4) = o1;
}

// ---------------- K2: softmax + top-2 + scatter, one wave per row ------------
// (unchanged from round 2 — passed)
__global__ __launch_bounds__(256)
void topk_kernel(float* __restrict__ probs,      // in: logits, out: probs
                 float* __restrict__ dispatch,
                 float* __restrict__ sel)
{
    const int lane = threadIdx.x & 63;
    const int wave = threadIdx.x >> 6;
    const int row  = blockIdx.x * 4 + wave;

    const float v = probs[(size_t)row * E + lane];

    // softmax (max-stabilized, matches jax.nn.softmax / np ref)
    float m = v;
#pragma unroll
    for (int off = 32; off > 0; off >>= 1)
        m = fmaxf(m, __shfl_xor(m, off, 64));
    const float p = expf(v - m);
    float s = p;
#pragma unroll
    for (int off = 32; off > 0; off >>= 1)
        s += __shfl_xor(s, off, 64);
    const float prob = p / s;
    probs[(size_t)row * E + lane] = prob;

    // top-1 (ties -> lower index, jax/np semantics)
    float bv = prob; int bi = lane;
#pragma unroll
    for (int off = 32; off > 0; off >>= 1) {
        const float ov = __shfl_xor(bv, off, 64);
        const int   oi = __shfl_xor(bi, off, 64);
        if (ov > bv || (ov == bv && oi < bi)) { bv = ov; bi = oi; }
    }
    // top-2: mask out argmax lane
    float cv = (lane == bi) ? -INFINITY : prob;
    int ci = lane;
#pragma unroll
    for (int off = 32; off > 0; off >>= 1) {
        const float ov = __shfl_xor(cv, off, 64);
        const int   oi = __shfl_xor(ci, off, 64);
        if (ov > cv || (ov == cv && oi < ci)) { cv = ov; ci = oi; }
    }

    const float sum2 = bv + cv;
    float dval = 0.f;
    if (lane == bi) dval = bv / sum2;
    if (lane == ci) dval = cv / sum2;
    dispatch[(size_t)row * E + lane] = dval;

    if (lane == 0) {
        float2 sv; sv.x = (float)bi; sv.y = (float)ci;
        *(float2*)(sel + (size_t)row * 2) = sv;
    }
}

extern "C" void kernel_launch(void* const* d_in, const int* in_sizes, int n_in,
                              void* d_out, int out_size, void* d_ws, size_t ws_size,
                              hipStream_t stream) {
    const float* x     = (const float*)d_in[0];
    const float* W     = (const float*)d_in[1];
    const float* scond = (const float*)d_in[2];
    const float* noise = (const float*)d_in[3];
    const int*   sidx  = (const int*)d_in[4];

    float* out      = (float*)d_out;
    float* dispatch = out;                              // [16384*64]
    float* probs    = out + (size_t)NROWS * E;          // [16384*64] (logits first)
    float* sel      = out + 2 * (size_t)NROWS * E;      // [16384*2] as float

    gemm_kernel<<<dim3(NROWS / 64), dim3(512), 0, stream>>>(
        x, W, scond, noise, sidx, probs);
    topk_kernel<<<dim3(NROWS / 4), dim3(256), 0, stream>>>(
        probs, dispatch, sel);
}

// Round 4
// 339.670 us; speedup vs baseline: 1.3087x; 1.3087x over previous
//
#include <hip/hip_runtime.h>
#include <math.h>

#define D        2048
#define E        64
#define NROWS    16384      // B*S = 4*4096
#define NSLICE   8
#define KSLICE   (D / NSLICE)   // 256
#define BK       32
#define TILES    (KSLICE / BK)  // 8
#define BM       128            // rows per block (ksplit kernel)
#define PARTIAL_BYTES ((size_t)NSLICE * NROWS * E * 4)   // 33.5 MB

// ============ K1 (primary): partial gemm, K-split across blocks ============
// 1024 blocks x 128 threads (2 waves). blockIdx: slice = bx&7, rowBlk = bx>>3.
// Per-thread 8 rows x 8 experts (64 acc) -> LDS traffic 1 B/FMA (vs 3 in r2).
// x tile in LDS transposed [kchunk][row] (chunk stride 129 float4s: staging
// writes bank-spread, reads conflict-free); W tile [k][e]. W stays in LDS
// (NO smem scalarization — r3 showed s_load in the loop serializes lgkmcnt).
__global__ __launch_bounds__(128, 2)
void gemm_ksplit(const float* __restrict__ x,
                 const float* __restrict__ W,
                 const float* __restrict__ scond,
                 const int* __restrict__ sidx,
                 float* __restrict__ partial)
{
    __shared__ float4 xsT[8 * 129];      // [kchunk][row(+pad)]
    __shared__ float  ws [BK * E];       // [k][e]

    const int tid   = threadIdx.x;
    const int slice = blockIdx.x & 7;
    const int rowBase = (blockIdx.x >> 3) * BM;
    const int kBase   = slice * KSLICE;

    const float factor = 1.0f + 0.1f * scond[sidx[0]];

    // staging maps
    const int sxr = tid >> 3;          // x row slot: rows sxr + 16*i
    const int sxc = tid & 7;           // x k-chunk (float4) within BK=32
    const int swe = tid & 63;          // W expert row
    const int swh = tid >> 6;          // W half: k-range 16*swh..16*swh+16

    // compute maps
    const int rg = tid & 15;           // rows rg + 16*i
    const int eg = tid >> 4;           // experts eg*8 .. eg*8+8   (0..7)

    float acc[8][8];
#pragma unroll
    for (int i = 0; i < 8; ++i)
#pragma unroll
        for (int j = 0; j < 8; ++j) acc[i][j] = 0.f;

    const float* xg = x + (size_t)rowBase * D + kBase;
    const float* wg = W + (size_t)swe * D + kBase + swh * 16;

    float4 xb[8], wb[4];
    // prefetch tile 0
#pragma unroll
    for (int i = 0; i < 8; ++i)
        xb[i] = *(const float4*)(xg + (size_t)(sxr + 16 * i) * D + (sxc << 2));
#pragma unroll
    for (int j = 0; j < 4; ++j)
        wb[j] = *(const float4*)(wg + (j << 2));

    for (int t = 0; t < TILES; ++t) {
        // regs -> LDS (x scaled by factor here, as in the passing r2 kernel)
#pragma unroll
        for (int i = 0; i < 8; ++i) {
            float4 v = xb[i];
            v.x *= factor; v.y *= factor; v.z *= factor; v.w *= factor;
            xsT[sxc * 129 + sxr + 16 * i] = v;
        }
#pragma unroll
        for (int j = 0; j < 4; ++j) {
            const int kk = swh * 16 + (j << 2);
            ws[(kk + 0) * E + swe] = wb[j].x;
            ws[(kk + 1) * E + swe] = wb[j].y;
            ws[(kk + 2) * E + swe] = wb[j].z;
            ws[(kk + 3) * E + swe] = wb[j].w;
        }
        __syncthreads();

        // prefetch tile t+1
        if (t + 1 < TILES) {
            const int k0 = (t + 1) * BK;
#pragma unroll
            for (int i = 0; i < 8; ++i)
                xb[i] = *(const float4*)(xg + (size_t)(sxr + 16 * i) * D + k0 + (sxc << 2));
#pragma unroll
            for (int j = 0; j < 4; ++j)
                wb[j] = *(const float4*)(wg + k0 + (j << 2));
        }

        // compute: per kg (4 k): 8 x-b128 + 8 w-b128 + 256 FMA
        const float4* ws4 = (const float4*)ws;
#pragma unroll
        for (int kg = 0; kg < 8; ++kg) {
            float4 xv[8];
#pragma unroll
            for (int i = 0; i < 8; ++i)
                xv[i] = xsT[kg * 129 + rg + 16 * i];
#pragma unroll
            for (int k = 0; k < 4; ++k) {
                const float4 wa = ws4[((kg << 2) + k) * 16 + (eg << 1)];
                const float4 wbq = ws4[((kg << 2) + k) * 16 + (eg << 1) + 1];
#pragma unroll
                for (int i = 0; i < 8; ++i) {
                    const float xk = ((const float*)&xv[i])[k];
                    acc[i][0] += xk * wa.x;  acc[i][1] += xk * wa.y;
                    acc[i][2] += xk * wa.z;  acc[i][3] += xk * wa.w;
                    acc[i][4] += xk * wbq.x; acc[i][5] += xk * wbq.y;
                    acc[i][6] += xk * wbq.z; acc[i][7] += xk * wbq.w;
                }
            }
        }
        __syncthreads();
    }

    // store partials: partial[slice][row][e]
    float* pbase = partial + (size_t)slice * NROWS * E;
#pragma unroll
    for (int i = 0; i < 8; ++i) {
        const int row = rowBase + rg + 16 * i;
        float4 a0, a1;
        a0.x = acc[i][0]; a0.y = acc[i][1]; a0.z = acc[i][2]; a0.w = acc[i][3];
        a1.x = acc[i][4]; a1.y = acc[i][5]; a1.z = acc[i][6]; a1.w = acc[i][7];
        *(float4*)(pbase + (size_t)row * E + (eg << 3))     = a0;
        *(float4*)(pbase + (size_t)row * E + (eg << 3) + 4) = a1;
    }
}

// ====== K2 (primary): reduce slices + noise + softmax + top2 + scatter ======
__global__ __launch_bounds__(256)
void reduce_topk(const float* __restrict__ partial,
                 const float* __restrict__ noise,
                 float* __restrict__ dispatch,
                 float* __restrict__ probs,
                 float* __restrict__ sel)
{
    const int lane = threadIdx.x & 63;
    const int wave = threadIdx.x >> 6;
    const int row  = blockIdx.x * 4 + wave;

    float v = 0.f;
#pragma unroll
    for (int s = 0; s < NSLICE; ++s)
        v += partial[(size_t)s * NROWS * E + (size_t)row * E + lane];
    v += 0.1f * noise[(size_t)row * E + lane];

    // softmax (max-stabilized)
    float m = v;
#pragma unroll
    for (int off = 32; off > 0; off >>= 1)
        m = fmaxf(m, __shfl_xor(m, off, 64));
    const float p = expf(v - m);
    float s = p;
#pragma unroll
    for (int off = 32; off > 0; off >>= 1)
        s += __shfl_xor(s, off, 64);
    const float prob = p / s;
    probs[(size_t)row * E + lane] = prob;

    // top-1 (ties -> lower index)
    float bv = prob; int bi = lane;
#pragma unroll
    for (int off = 32; off > 0; off >>= 1) {
        const float ov = __shfl_xor(bv, off, 64);
        const int   oi = __shfl_xor(bi, off, 64);
        if (ov > bv || (ov == bv && oi < bi)) { bv = ov; bi = oi; }
    }
    float cv = (lane == bi) ? -INFINITY : prob;
    int ci = lane;
#pragma unroll
    for (int off = 32; off > 0; off >>= 1) {
        const float ov = __shfl_xor(cv, off, 64);
        const int   oi = __shfl_xor(ci, off, 64);
        if (ov > cv || (ov == cv && oi < ci)) { cv = ov; ci = oi; }
    }

    const float sum2 = bv + cv;
    float dval = 0.f;
    if (lane == bi) dval = bv / sum2;
    if (lane == ci) dval = cv / sum2;
    dispatch[(size_t)row * E + lane] = dval;

    if (lane == 0) {
        float2 sv; sv.x = (float)bi; sv.y = (float)ci;
        *(float2*)(sel + (size_t)row * 2) = sv;
    }
}

// ================== Fallback pair (round-2, known-good) =====================
__global__ __launch_bounds__(256)
void gemm_r2(const float* __restrict__ x, const float* __restrict__ W,
             const float* __restrict__ scond, const float* __restrict__ noise,
             const int* __restrict__ sidx, float* __restrict__ logits_out)
{
    __shared__ float4 xs[32][17];
    __shared__ float4 wsh[64][16];
    const int tid = threadIdx.x;
    const int rowBase = blockIdx.x * 32;
    const float factor = 1.0f + 0.1f * scond[sidx[0]];
    const int xk = tid & 15, xr = tid >> 4, we = tid & 63, wk = tid >> 6;
    const int eg = tid & 15, rg = tid >> 4, e0 = eg << 2;
    float acc[2][4];
#pragma unroll
    for (int i = 0; i < 2; ++i)
#pragma unroll
        for (int j = 0; j < 4; ++j) acc[i][j] = 0.f;
    const float* xg = x + (size_t)rowBase * D;
    float4 xb[2], wb[4];
#pragma unroll
    for (int i = 0; i < 2; ++i)
        xb[i] = *(const float4*)(xg + (xr + 16 * i) * D + (xk << 2));
#pragma unroll
    for (int j = 0; j < 4; ++j)
        wb[j] = *(const float4*)(W + we * D + (wk << 4) + (j << 2));
    for (int t = 0; t < 32; ++t) {
#pragma unroll
        for (int i = 0; i < 2; ++i) {
            float4 v = xb[i];
            v.x *= factor; v.y *= factor; v.z *= factor; v.w *= factor;
            xs[xr + 16 * i][xk] = v;
        }
        float* wsf = (float*)wsh;
#pragma unroll
        for (int j = 0; j < 4; ++j) {
            const int kk = (wk << 4) + (j << 2);
            wsf[(kk + 0) * E + we] = wb[j].x;
            wsf[(kk + 1) * E + we] = wb[j].y;
            wsf[(kk + 2) * E + we] = wb[j].z;
            wsf[(kk + 3) * E + we] = wb[j].w;
        }
        __syncthreads();
        if (t + 1 < 32) {
            const int k0 = (t + 1) * 64;
#pragma unroll
            for (int i = 0; i < 2; ++i)
                xb[i] = *(const float4*)(xg + (xr + 16 * i) * D + k0 + (xk << 2));
#pragma unroll
            for (int j = 0; j < 4; ++j)
                wb[j] = *(const float4*)(W + we * D + k0 + (wk << 4) + (j << 2));
        }
#pragma unroll
        for (int kg = 0; kg < 16; ++kg) {
            float4 xv[2], wv[4];
#pragma unroll
            for (int i = 0; i < 2; ++i) xv[i] = xs[rg + 16 * i][kg];
#pragma unroll
            for (int c = 0; c < 4; ++c) wv[c] = wsh[(kg << 2) + c][eg];
#pragma unroll
            for (int i = 0; i < 2; ++i) {
                const float x0 = xv[i].x, x1 = xv[i].y, x2 = xv[i].z, x3 = xv[i].w;
                acc[i][0] += x0 * wv[0].x; acc[i][1] += x0 * wv[0].y;
                acc[i][2] += x0 * wv[0].z; acc[i][3] += x0 * wv[0].w;
                acc[i][0] += x1 * wv[1].x; acc[i][1] += x1 * wv[1].y;
                acc[i][2] += x1 * wv[1].z; acc[i][3] += x1 * wv[1].w;
                acc[i][0] += x2 * wv[2].x; acc[i][1] += x2 * wv[2].y;
                acc[i][2] += x2 * wv[2].z; acc[i][3] += x2 * wv[2].w;
                acc[i][0] += x3 * wv[3].x; acc[i][1] += x3 * wv[3].y;
                acc[i][2] += x3 * wv[3].z; acc[i][3] += x3 * wv[3].w;
            }
        }
        __syncthreads();
    }
#pragma unroll
    for (int i = 0; i < 2; ++i) {
        const int gRow = rowBase + rg + 16 * i;
        const float4 nz = *(const float4*)(noise + (size_t)gRow * E + e0);
        float4 o;
        o.x = acc[i][0] + 0.1f * nz.x; o.y = acc[i][1] + 0.1f * nz.y;
        o.z = acc[i][2] + 0.1f * nz.z; o.w = acc[i][3] + 0.1f * nz.w;
        *(float4*)(logits_out + (size_t)gRow * E + e0) = o;
    }
}

__global__ __launch_bounds__(256)
void topk_r2(float* __restrict__ probs, float* __restrict__ dispatch,
             float* __restrict__ sel)
{
    const int lane = threadIdx.x & 63;
    const int wave = threadIdx.x >> 6;
    const int row  = blockIdx.x * 4 + wave;
    const float v = probs[(size_t)row * E + lane];
    float m = v;
#pragma unroll
    for (int off = 32; off > 0; off >>= 1)
        m = fmaxf(m, __shfl_xor(m, off, 64));
    const float p = expf(v - m);
    float s = p;
#pragma unroll
    for (int off = 32; off > 0; off >>= 1)
        s += __shfl_xor(s, off, 64);
    const float prob = p / s;
    probs[(size_t)row * E + lane] = prob;
    float bv = prob; int bi = lane;
#pragma unroll
    for (int off = 32; off > 0; off >>= 1) {
        const float ov = __shfl_xor(bv, off, 64);
        const int   oi = __shfl_xor(bi, off, 64);
        if (ov > bv || (ov == bv && oi < bi)) { bv = ov; bi = oi; }
    }
    float cv = (lane == bi) ? -INFINITY : prob;
    int ci = lane;
#pragma unroll
    for (int off = 32; off > 0; off >>= 1) {
        const float ov = __shfl_xor(cv, off, 64);
        const int   oi = __shfl_xor(ci, off, 64);
        if (ov > cv || (ov == cv && oi < ci)) { cv = ov; ci = oi; }
    }
    const float sum2 = bv + cv;
    float dval = 0.f;
    if (lane == bi) dval = bv / sum2;
    if (lane == ci) dval = cv / sum2;
    dispatch[(size_t)row * E + lane] = dval;
    if (lane == 0) {
        float2 sv; sv.x = (float)bi; sv.y = (float)ci;
        *(float2*)(sel + (size_t)row * 2) = sv;
    }
}

extern "C" void kernel_launch(void* const* d_in, const int* in_sizes, int n_in,
                              void* d_out, int out_size, void* d_ws, size_t ws_size,
                              hipStream_t stream) {
    const float* x     = (const float*)d_in[0];
    const float* W     = (const float*)d_in[1];
    const float* scond = (const float*)d_in[2];
    const float* noise = (const float*)d_in[3];
    const int*   sidx  = (const int*)d_in[4];

    float* out      = (float*)d_out;
    float* dispatch = out;
    float* probs    = out + (size_t)NROWS * E;
    float* sel      = out + 2 * (size_t)NROWS * E;

    if (ws_size >= PARTIAL_BYTES) {
        float* partial = (float*)d_ws;
        gemm_ksplit<<<dim3((NROWS / BM) * NSLICE), dim3(128), 0, stream>>>(
            x, W, scond, sidx, partial);
        reduce_topk<<<dim3(NROWS / 4), dim3(256), 0, stream>>>(
            partial, noise, dispatch, probs, sel);
    } else {
        gemm_r2<<<dim3(NROWS / 32), dim3(256), 0, stream>>>(
            x, W, scond, noise, sidx, probs);
        topk_r2<<<dim3(NROWS / 4), dim3(256), 0, stream>>>(
            probs, dispatch, sel);
    }
}

// Round 6
// 220.555 us; speedup vs baseline: 2.0154x; 1.5401x over previous
//
#include <hip/hip_runtime.h>
#include <math.h>

#define D        2048
#define E        64
#define NROWS    16384              // B*S = 4*4096
#define NSLICE   4
#define KSLICE   (D / NSLICE)       // 512
#define BK       32
#define TILES    (KSLICE / BK)      // 16
#define BM       32                 // rows per block
#define XSTR     36                 // x tile row stride (floats)
#define OSTR     68                 // epilogue tile row stride (floats)
#define PARTIAL_BYTES ((size_t)NSLICE * NROWS * E * 4)   // 16.8 MB

// ============ K1: partial gemm, 1-wave blocks, broadcast-tile reads ==========
// Grid 2048 x 64 threads (8 waves/CU). Per-lane tile 4 rows x 8 experts.
// lane: rg=l&7 -> rows {rg+8i}, eg=l>>3 -> experts [8eg,8eg+8).
// x LDS reads are 8-way broadcast (bank-free); W reads 2-way (free) ->
// ~10:1 fmac:ds ratio, VALU-bound. Single wave per block: DS pipe in-order
// per wave -> no barriers. Epilogue stages tile in LDS for coalesced stores.
// R5 BUG FIX: each thread now stages 16 x-floats (4xfloat4) -> full 32x32
// tile coverage (r5 staged only k=0..15; k=16..31 was uninitialized LDS).
__global__ __launch_bounds__(64)
void gemm_ks(const float* __restrict__ x,
             const float* __restrict__ W,
             const float* __restrict__ scond,
             const int* __restrict__ sidx,
             float* __restrict__ partial)
{
    // xs: BM*XSTR = 1152 f, ws: BK*E = 2048 f; epilogue reuses pool as 32x68.
    __shared__ float smem[BM * XSTR + BK * E];   // 12.5 KB
    float* xs = smem;
    float* ws = smem + BM * XSTR;

    const int l = threadIdx.x;
    const int slice   = blockIdx.x & (NSLICE - 1);
    const int rowBase = (blockIdx.x >> 2) * BM;
    const int kBase   = slice * KSLICE;

    const float factor = 1.0f + 0.1f * scond[sidx[0]];

    // staging maps: x row = l>>1, 16-float half = (l&1)*16; W expert row = l
    const int sxr = l >> 1;
    const int sxh = (l & 1) << 4;

    // compute maps
    const int rg = l & 7;
    const int eg = l >> 3;

    float acc[4][8];
#pragma unroll
    for (int i = 0; i < 4; ++i)
#pragma unroll
        for (int j = 0; j < 8; ++j) acc[i][j] = 0.f;

    const float* xg = x + (size_t)rowBase * D + kBase;
    const float* wg = W + (size_t)l * D + kBase;   // thread stages expert row l

    float4 xb[4], wb[8];
    // prefetch tile 0 (full coverage: 64 thr x 16 f = 1024 f = 32x32 tile)
#pragma unroll
    for (int j = 0; j < 4; ++j)
        xb[j] = *(const float4*)(xg + sxr * D + sxh + (j << 2));
#pragma unroll
    for (int j = 0; j < 8; ++j)
        wb[j] = *(const float4*)(wg + (j << 2));

    for (int t = 0; t < TILES; ++t) {
        // regs -> LDS. x scaled by factor at staging (= ref's router_input).
#pragma unroll
        for (int j = 0; j < 4; ++j) {
            float4 v = xb[j];
            v.x *= factor; v.y *= factor; v.z *= factor; v.w *= factor;
            *(float4*)&xs[sxr * XSTR + sxh + (j << 2)] = v;
        }
#pragma unroll
        for (int j = 0; j < 8; ++j) {       // W -> [k][e], 2-way banks
            const int k4 = j << 2;
            ws[(k4 + 0) * E + l] = wb[j].x;
            ws[(k4 + 1) * E + l] = wb[j].y;
            ws[(k4 + 2) * E + l] = wb[j].z;
            ws[(k4 + 3) * E + l] = wb[j].w;
        }

        // prefetch tile t+1 (hidden behind the fmac block below)
        if (t + 1 < TILES) {
            const int k0 = (t + 1) * BK;
#pragma unroll
            for (int j = 0; j < 4; ++j)
                xb[j] = *(const float4*)(xg + sxr * D + k0 + sxh + (j << 2));
#pragma unroll
            for (int j = 0; j < 8; ++j)
                wb[j] = *(const float4*)(wg + k0 + (j << 2));
        }

        // compute: per k-quad 12 ds_read_b128 (broadcast-heavy) + 128 fmac
#pragma unroll
        for (int kc = 0; kc < 8; ++kc) {
            float4 xv[4];
#pragma unroll
            for (int i = 0; i < 4; ++i)
                xv[i] = *(const float4*)&xs[(rg + 8 * i) * XSTR + (kc << 2)];
            float4 wv[8];
#pragma unroll
            for (int k = 0; k < 4; ++k) {
                wv[2 * k]     = *(const float4*)&ws[((kc << 2) + k) * E + (eg << 3)];
                wv[2 * k + 1] = *(const float4*)&ws[((kc << 2) + k) * E + (eg << 3) + 4];
            }
#pragma unroll
            for (int k = 0; k < 4; ++k) {
#pragma unroll
                for (int i = 0; i < 4; ++i) {
                    const float xk = ((const float*)&xv[i])[k];
                    acc[i][0] += xk * wv[2 * k].x;
                    acc[i][1] += xk * wv[2 * k].y;
                    acc[i][2] += xk * wv[2 * k].z;
                    acc[i][3] += xk * wv[2 * k].w;
                    acc[i][4] += xk * wv[2 * k + 1].x;
                    acc[i][5] += xk * wv[2 * k + 1].y;
                    acc[i][6] += xk * wv[2 * k + 1].z;
                    acc[i][7] += xk * wv[2 * k + 1].w;
                }
            }
        }
    }

    // ---- epilogue: stage tile in LDS, then fully-coalesced float4 stores ----
#pragma unroll
    for (int i = 0; i < 4; ++i) {
        float4 a0, a1;
        a0.x = acc[i][0]; a0.y = acc[i][1]; a0.z = acc[i][2]; a0.w = acc[i][3];
        a1.x = acc[i][4]; a1.y = acc[i][5]; a1.z = acc[i][6]; a1.w = acc[i][7];
        *(float4*)&smem[(rg + 8 * i) * OSTR + (eg << 3)]     = a0;
        *(float4*)&smem[(rg + 8 * i) * OSTR + (eg << 3) + 4] = a1;
    }
    float* pbase = partial + (size_t)slice * NROWS * E + (size_t)rowBase * E;
#pragma unroll
    for (int j = 0; j < 8; ++j) {
        const int p   = (j << 6) + l;        // float4 index 0..511 in tile
        const int row = p >> 4;
        const int c4  = p & 15;
        const float4 vv = *(const float4*)&smem[row * OSTR + (c4 << 2)];
        *(float4*)(pbase + ((size_t)p << 2)) = vv;
    }
}

// ====== K2: reduce slices + noise + softmax + top2 + scatter (r4, passed) ====
__global__ __launch_bounds__(256)
void reduce_topk(const float* __restrict__ partial,
                 const float* __restrict__ noise,
                 float* __restrict__ dispatch,
                 float* __restrict__ probs,
                 float* __restrict__ sel)
{
    const int lane = threadIdx.x & 63;
    const int wave = threadIdx.x >> 6;
    const int row  = blockIdx.x * 4 + wave;

    float v = 0.f;
#pragma unroll
    for (int s = 0; s < NSLICE; ++s)
        v += partial[(size_t)s * NROWS * E + (size_t)row * E + lane];
    v += 0.1f * noise[(size_t)row * E + lane];

    float m = v;
#pragma unroll
    for (int off = 32; off > 0; off >>= 1)
        m = fmaxf(m, __shfl_xor(m, off, 64));
    const float p = expf(v - m);
    float s = p;
#pragma unroll
    for (int off = 32; off > 0; off >>= 1)
        s += __shfl_xor(s, off, 64);
    const float prob = p / s;
    probs[(size_t)row * E + lane] = prob;

    float bv = prob; int bi = lane;
#pragma unroll
    for (int off = 32; off > 0; off >>= 1) {
        const float ov = __shfl_xor(bv, off, 64);
        const int   oi = __shfl_xor(bi, off, 64);
        if (ov > bv || (ov == bv && oi < bi)) { bv = ov; bi = oi; }
    }
    float cv = (lane == bi) ? -INFINITY : prob;
    int ci = lane;
#pragma unroll
    for (int off = 32; off > 0; off >>= 1) {
        const float ov = __shfl_xor(cv, off, 64);
        const int   oi = __shfl_xor(ci, off, 64);
        if (ov > cv || (ov == cv && oi < ci)) { cv = ov; ci = oi; }
    }

    const float sum2 = bv + cv;
    float dval = 0.f;
    if (lane == bi) dval = bv / sum2;
    if (lane == ci) dval = cv / sum2;
    dispatch[(size_t)row * E + lane] = dval;

    if (lane == 0) {
        float2 sv; sv.x = (float)bi; sv.y = (float)ci;
        *(float2*)(sel + (size_t)row * 2) = sv;
    }
}

// ================== Fallback pair (round-2, known-good) =====================
__global__ __launch_bounds__(256)
void gemm_r2(const float* __restrict__ x, const float* __restrict__ W,
             const float* __restrict__ scond, const float* __restrict__ noise,
             const int* __restrict__ sidx, float* __restrict__ logits_out)
{
    __shared__ float4 xsb[32][17];
    __shared__ float4 wsh[64][16];
    const int tid = threadIdx.x;
    const int rowBase = blockIdx.x * 32;
    const float factor = 1.0f + 0.1f * scond[sidx[0]];
    const int xk = tid & 15, xr = tid >> 4, we = tid & 63, wk = tid >> 6;
    const int eg = tid & 15, rg = tid >> 4, e0 = eg << 2;
    float acc[2][4];
#pragma unroll
    for (int i = 0; i < 2; ++i)
#pragma unroll
        for (int j = 0; j < 4; ++j) acc[i][j] = 0.f;
    const float* xg = x + (size_t)rowBase * D;
    float4 xb[2], wb[4];
#pragma unroll
    for (int i = 0; i < 2; ++i)
        xb[i] = *(const float4*)(xg + (xr + 16 * i) * D + (xk << 2));
#pragma unroll
    for (int j = 0; j < 4; ++j)
        wb[j] = *(const float4*)(W + we * D + (wk << 4) + (j << 2));
    for (int t = 0; t < 32; ++t) {
#pragma unroll
        for (int i = 0; i < 2; ++i) {
            float4 v = xb[i];
            v.x *= factor; v.y *= factor; v.z *= factor; v.w *= factor;
            xsb[xr + 16 * i][xk] = v;
        }
        float* wsf = (float*)wsh;
#pragma unroll
        for (int j = 0; j < 4; ++j) {
            const int kk = (wk << 4) + (j << 2);
            wsf[(kk + 0) * E + we] = wb[j].x;
            wsf[(kk + 1) * E + we] = wb[j].y;
            wsf[(kk + 2) * E + we] = wb[j].z;
            wsf[(kk + 3) * E + we] = wb[j].w;
        }
        __syncthreads();
        if (t + 1 < 32) {
            const int k0 = (t + 1) * 64;
#pragma unroll
            for (int i = 0; i < 2; ++i)
                xb[i] = *(const float4*)(xg + (xr + 16 * i) * D + k0 + (xk << 2));
#pragma unroll
            for (int j = 0; j < 4; ++j)
                wb[j] = *(const float4*)(W + we * D + k0 + (wk << 4) + (j << 2));
        }
#pragma unroll
        for (int kg = 0; kg < 16; ++kg) {
            float4 xv[2], wv[4];
#pragma unroll
            for (int i = 0; i < 2; ++i) xv[i] = xsb[rg + 16 * i][kg];
#pragma unroll
            for (int c = 0; c < 4; ++c) wv[c] = wsh[(kg << 2) + c][eg];
#pragma unroll
            for (int i = 0; i < 2; ++i) {
                const float x0 = xv[i].x, x1 = xv[i].y, x2 = xv[i].z, x3 = xv[i].w;
                acc[i][0] += x0 * wv[0].x; acc[i][1] += x0 * wv[0].y;
                acc[i][2] += x0 * wv[0].z; acc[i][3] += x0 * wv[0].w;
                acc[i][0] += x1 * wv[1].x; acc[i][1] += x1 * wv[1].y;
                acc[i][2] += x1 * wv[1].z; acc[i][3] += x1 * wv[1].w;
                acc[i][0] += x2 * wv[2].x; acc[i][1] += x2 * wv[2].y;
                acc[i][2] += x2 * wv[2].z; acc[i][3] += x2 * wv[2].w;
                acc[i][0] += x3 * wv[3].x; acc[i][1] += x3 * wv[3].y;
                acc[i][2] += x3 * wv[3].z; acc[i][3] += x3 * wv[3].w;
            }
        }
        __syncthreads();
    }
#pragma unroll
    for (int i = 0; i < 2; ++i) {
        const int gRow = rowBase + rg + 16 * i;
        const float4 nz = *(const float4*)(noise + (size_t)gRow * E + e0);
        float4 o;
        o.x = acc[i][0] + 0.1f * nz.x; o.y = acc[i][1] + 0.1f * nz.y;
        o.z = acc[i][2] + 0.1f * nz.z; o.w = acc[i][3] + 0.1f * nz.w;
        *(float4*)(logits_out + (size_t)gRow * E + e0) = o;
    }
}

__global__ __launch_bounds__(256)
void topk_r2(float* __restrict__ probs, float* __restrict__ dispatch,
             float* __restrict__ sel)
{
    const int lane = threadIdx.x & 63;
    const int wave = threadIdx.x >> 6;
    const int row  = blockIdx.x * 4 + wave;
    const float v = probs[(size_t)row * E + lane];
    float m = v;
#pragma unroll
    for (int off = 32; off > 0; off >>= 1)
        m = fmaxf(m, __shfl_xor(m, off, 64));
    const float p = expf(v - m);
    float s = p;
#pragma unroll
    for (int off = 32; off > 0; off >>= 1)
        s += __shfl_xor(s, off, 64);
    const float prob = p / s;
    probs[(size_t)row * E + lane] = prob;
    float bv = prob; int bi = lane;
#pragma unroll
    for (int off = 32; off > 0; off >>= 1) {
        const float ov = __shfl_xor(bv, off, 64);
        const int   oi = __shfl_xor(bi, off, 64);
        if (ov > bv || (ov == bv && oi < bi)) { bv = ov; bi = oi; }
    }
    float cv = (lane == bi) ? -INFINITY : prob;
    int ci = lane;
#pragma unroll
    for (int off = 32; off > 0; off >>= 1) {
        const float ov = __shfl_xor(cv, off, 64);
        const int   oi = __shfl_xor(ci, off, 64);
        if (ov > cv || (ov == cv && oi < ci)) { cv = ov; ci = oi; }
    }
    const float sum2 = bv + cv;
    float dval = 0.f;
    if (lane == bi) dval = bv / sum2;
    if (lane == ci) dval = cv / sum2;
    dispatch[(size_t)row * E + lane] = dval;
    if (lane == 0) {
        float2 sv; sv.x = (float)bi; sv.y = (float)ci;
        *(float2*)(sel + (size_t)row * 2) = sv;
    }
}

extern "C" void kernel_launch(void* const* d_in, const int* in_sizes, int n_in,
                              void* d_out, int out_size, void* d_ws, size_t ws_size,
                              hipStream_t stream) {
    const float* x     = (const float*)d_in[0];
    const float* W     = (const float*)d_in[1];
    const float* scond = (const float*)d_in[2];
    const float* noise = (const float*)d_in[3];
    const int*   sidx  = (const int*)d_in[4];

    float* out      = (float*)d_out;
    float* dispatch = out;
    float* probs    = out + (size_t)NROWS * E;
    float* sel      = out + 2 * (size_t)NROWS * E;

    if (ws_size >= PARTIAL_BYTES) {
        float* partial = (float*)d_ws;
        gemm_ks<<<dim3((NROWS / BM) * NSLICE), dim3(64), 0, stream>>>(
            x, W, scond, sidx, partial);
        reduce_topk<<<dim3(NROWS / 4), dim3(256), 0, stream>>>(
            partial, noise, dispatch, probs, sel);
    } else {
        gemm_r2<<<dim3(NROWS / 32), dim3(256), 0, stream>>>(
            x, W, scond, noise, sidx, probs);
        topk_r2<<<dim3(NROWS / 4), dim3(256), 0, stream>>>(
            probs, dispatch, sel);
    }
}